// Round 11
// baseline (955.821 us; speedup 1.0000x reference)
//
#include <hip/hip_runtime.h>
#include <hip/hip_bf16.h>

// Problem constants
#define B_ROWS 16384
#define XC     10242      // 1 rate + 25 genre + 2186 director + 8030 actor
#define NGENRE 25
#define NDIR   2186
#define NACT   8030
#define EMB    32
#define KT_TOTAL 321      // ceil(10242/32) k-tiles of 32
#define OUTC   128
#define NCOLS  112        // slab cols: 96 emb + 3 counts + pad
#define PART_STRIDE ((size_t)B_ROWS * NCOLS)
#define WFRAG_BYTES ((size_t)KT_TOTAL * 4 * 64 * 16)   // 1.31 MB

typedef short bf16x8 __attribute__((ext_vector_type(8)));
typedef float f32x4  __attribute__((ext_vector_type(4)));
typedef int   i32x4a __attribute__((ext_vector_type(4), aligned(4)));

// ===========================================================================
// Prep (proven): pre-convert block-diagonal W into bf16 B-fragments,
// fragment-linear. B-frag: lane l holds B[k=kt*32+(l>>4)*8+j][n=l&15].
// 4 slots/kt; boundary tiles (0: genre|director, 69: director|actor) use all
// 4 pre-masked; interior tiles use slots 0,1.
// ===========================================================================
__global__ void prep_wfrag(const float* __restrict__ wg,
                           const float* __restrict__ wd,
                           const float* __restrict__ wa,
                           uint4* __restrict__ Wfrag) {
  const int kt = blockIdx.x;
  const int s  = threadIdx.x >> 6;       // slot 0..3
  const int l  = threadIdx.x & 63;
  const int n  = l & 15;
  const int k0 = kt * 32 + ((l >> 4) << 3);

  unsigned short v[8];
#pragma unroll
  for (int j = 0; j < 8; ++j) {
    const int k = k0 + j;
    float f = 0.f;
    if (kt == 0) {
      if (s < 2) { if (k >= 1 && k < 26) f = wg[(s * 16 + n) * NGENRE + (k - 1)]; }
      else       { if (k >= 26)          f = wd[((s - 2) * 16 + n) * NDIR + (k - 26)]; }
    } else if (kt < 69) {
      if (s < 2) f = wd[(s * 16 + n) * NDIR + (k - 26)];
    } else if (kt == 69) {
      if (s < 2) { if (k < 2212)  f = wd[(s * 16 + n) * NDIR + (k - 26)]; }
      else       { if (k >= 2212) f = wa[((s - 2) * 16 + n) * NACT + (k - 2212)]; }
    } else if (kt < 320) {
      if (s < 2) f = wa[(s * 16 + n) * NACT + (k - 2212)];
    } else {
      if (s < 2 && k < XC) f = wa[(s * 16 + n) * NACT + (k - 2212)];
    }
    __hip_bfloat16 h = __float2bfloat16(f);
    v[j] = *reinterpret_cast<unsigned short*>(&h);
  }
  union { unsigned short u[8]; uint4 q; } cv;
#pragma unroll
  for (int j = 0; j < 8; ++j) cv.u[j] = v[j];
  Wfrag[((size_t)kt * 4 + s) * 64 + l] = cv.q;
}

// ===========================================================================
// Main. R11 structural fix: vmcnt is a FIFO count, so consuming a late-issued
// load drains all earlier ones. Previous versions consumed per-tile B-loads
// (issued late) before prefetched x (issued early) => full drain every tile.
// Now: branch-free segment-interior runs, groups of 4 tiles, issue order ==
// consumption order ([x(t);b(t)] interleaved) => monotone waits, prefetches
// stay in flight. Boundary tiles (0/69/320) + remainders via slow path.
// A-frag: lane holds A[m=lane&15][k=(lane>>4)*8+j]; C/D row=(lane>>4)*4+j,
// col=lane&15. Pack: (x0 + (x1<<16)) * 0x3F80 (exact for x in {0,1}).
// ===========================================================================
template<int KS>
__global__ __launch_bounds__(256, 4) void main_mm(const int* __restrict__ x,
                                                  const uint4* __restrict__ Wfrag,
                                                  float* __restrict__ part) {
  constexpr int PER = (((KT_TOTAL + KS - 1) / KS) + 3) & ~3;
  const int t    = threadIdx.x;
  const int rb   = blockIdx.x & 255;
  const int ks   = blockIdx.x >> 8;
  const int ktA  = ks * PER;
  const int ktB  = (ktA + PER < KT_TOTAL) ? ktA + PER : KT_TOTAL;
  const int lane = t & 63;
  const int w    = t >> 6;
  const int lo   = lane & 15, hi = lane >> 4;
  const int* xrow = x + (size_t)(rb * 64 + w * 16 + lo) * XC;

  f32x4 accG0 = {0,0,0,0}, accG1 = {0,0,0,0};
  f32x4 accD0 = {0,0,0,0}, accD1 = {0,0,0,0};
  f32x4 accA0 = {0,0,0,0}, accA1 = {0,0,0,0};
  f32x4 accI  = {0,0,0,0};

  auto load_x8 = [&](int kt, int* dst) {
    int k0 = kt * 32 + hi * 8;
    if (kt < 320) {          // wave-uniform in-bounds: k0+7 <= 10239 < XC
      i32x4a a = *reinterpret_cast<const i32x4a*>(xrow + k0);
      i32x4a b = *reinterpret_cast<const i32x4a*>(xrow + k0 + 4);
      dst[0]=a[0]; dst[1]=a[1]; dst[2]=a[2]; dst[3]=a[3];
      dst[4]=b[0]; dst[5]=b[1]; dst[6]=b[2]; dst[7]=b[3];
    } else {
#pragma unroll
      for (int j = 0; j < 8; ++j) dst[j] = (k0 + j < XC) ? xrow[k0 + j] : 0;
    }
  };
  auto packa = [&](const int* cx) -> bf16x8 {
    union { unsigned int w4[4]; bf16x8 v; } af;
#pragma unroll
    for (int i = 0; i < 4; ++i)
      af.w4[i] = ((unsigned)cx[2*i] + ((unsigned)cx[2*i+1] << 16)) * 0x3F80u;
    return af.v;
  };
  auto bload = [&](int kt, int s) -> bf16x8 {
    union { uint4 q; bf16x8 v; } c;
    c.q = Wfrag[((size_t)kt * 4 + s) * 64 + lane];
    return c.v;
  };
  auto mkconst = [&](bool on) -> bf16x8 {
    union { unsigned int w4[4]; bf16x8 v; } c;
    unsigned int u = on ? 0x3F803F80u : 0u;
    c.w4[0]=u; c.w4[1]=u; c.w4[2]=u; c.w4[3]=u;
    return c.v;
  };
  const bf16x8 ivD = mkconst(lo == 1);
  const bf16x8 ivA = mkconst(lo == 2);

  // Slow path: handles any single tile incl. boundary specials (runtime kt).
  auto slow_tile = [&](int kt) {
    int xv[8];
    load_x8(kt, xv);
    bf16x8 a = packa(xv);
    const int kb = kt * 32 + hi * 8;
    if (kt == 0) {
      accG0 = __builtin_amdgcn_mfma_f32_16x16x32_bf16(a, bload(0,0), accG0, 0,0,0);
      accG1 = __builtin_amdgcn_mfma_f32_16x16x32_bf16(a, bload(0,1), accG1, 0,0,0);
      accD0 = __builtin_amdgcn_mfma_f32_16x16x32_bf16(a, bload(0,2), accD0, 0,0,0);
      accD1 = __builtin_amdgcn_mfma_f32_16x16x32_bf16(a, bload(0,3), accD1, 0,0,0);
      union { unsigned short u[8]; bf16x8 v; } iv;
#pragma unroll
      for (int j = 0; j < 8; ++j) {
        int k = kb + j;
        bool on = (lo == 0) ? (k >= 1 && k < 26) : (lo == 1) ? (k >= 26) : false;
        iv.u[j] = on ? (unsigned short)0x3F80 : (unsigned short)0;
      }
      accI = __builtin_amdgcn_mfma_f32_16x16x32_bf16(a, iv.v, accI, 0,0,0);
    } else if (kt < 69) {
      accD0 = __builtin_amdgcn_mfma_f32_16x16x32_bf16(a, bload(kt,0), accD0, 0,0,0);
      accD1 = __builtin_amdgcn_mfma_f32_16x16x32_bf16(a, bload(kt,1), accD1, 0,0,0);
      accI  = __builtin_amdgcn_mfma_f32_16x16x32_bf16(a, ivD, accI, 0,0,0);
    } else if (kt == 69) {
      accD0 = __builtin_amdgcn_mfma_f32_16x16x32_bf16(a, bload(69,0), accD0, 0,0,0);
      accD1 = __builtin_amdgcn_mfma_f32_16x16x32_bf16(a, bload(69,1), accD1, 0,0,0);
      accA0 = __builtin_amdgcn_mfma_f32_16x16x32_bf16(a, bload(69,2), accA0, 0,0,0);
      accA1 = __builtin_amdgcn_mfma_f32_16x16x32_bf16(a, bload(69,3), accA1, 0,0,0);
      union { unsigned short u[8]; bf16x8 v; } iv;
#pragma unroll
      for (int j = 0; j < 8; ++j) {
        int k = kb + j;
        bool on = (lo == 1) ? (k < 2212) : (lo == 2) ? (k >= 2212) : false;
        iv.u[j] = on ? (unsigned short)0x3F80 : (unsigned short)0;
      }
      accI = __builtin_amdgcn_mfma_f32_16x16x32_bf16(a, iv.v, accI, 0,0,0);
    } else if (kt < 320) {
      accA0 = __builtin_amdgcn_mfma_f32_16x16x32_bf16(a, bload(kt,0), accA0, 0,0,0);
      accA1 = __builtin_amdgcn_mfma_f32_16x16x32_bf16(a, bload(kt,1), accA1, 0,0,0);
      accI  = __builtin_amdgcn_mfma_f32_16x16x32_bf16(a, ivA, accI, 0,0,0);
    } else {
      accA0 = __builtin_amdgcn_mfma_f32_16x16x32_bf16(a, bload(320,0), accA0, 0,0,0);
      accA1 = __builtin_amdgcn_mfma_f32_16x16x32_bf16(a, bload(320,1), accA1, 0,0,0);
      union { unsigned short u[8]; bf16x8 v; } iv;
#pragma unroll
      for (int j = 0; j < 8; ++j) {
        int k = kb + j;
        iv.u[j] = (lo == 2 && k < XC) ? (unsigned short)0x3F80 : (unsigned short)0;
      }
      accI = __builtin_amdgcn_mfma_f32_16x16x32_bf16(a, iv.v, accI, 0,0,0);
    }
  };

  // Branch-free interior run: groups of 4 tiles, issue [x(t);b(t)] x4 in
  // consumption order => monotone vmcnt, all younger prefetches stay live.
  auto run4 = [&](int ktS, int ktE, f32x4& s0, f32x4& s1, const bf16x8 ivS) {
    for (int g = ktS; g < ktE; g += 4) {
      int x0[8], x1[8], x2[8], x3[8];
      bf16x8 b00, b01, b10, b11, b20, b21, b30, b31;
      load_x8(g,     x0); b00 = bload(g,     0); b01 = bload(g,     1);
      load_x8(g + 1, x1); b10 = bload(g + 1, 0); b11 = bload(g + 1, 1);
      load_x8(g + 2, x2); b20 = bload(g + 2, 0); b21 = bload(g + 2, 1);
      load_x8(g + 3, x3); b30 = bload(g + 3, 0); b31 = bload(g + 3, 1);
      bf16x8 a;
      a = packa(x0);
      s0 = __builtin_amdgcn_mfma_f32_16x16x32_bf16(a, b00, s0, 0,0,0);
      s1 = __builtin_amdgcn_mfma_f32_16x16x32_bf16(a, b01, s1, 0,0,0);
      accI = __builtin_amdgcn_mfma_f32_16x16x32_bf16(a, ivS, accI, 0,0,0);
      a = packa(x1);
      s0 = __builtin_amdgcn_mfma_f32_16x16x32_bf16(a, b10, s0, 0,0,0);
      s1 = __builtin_amdgcn_mfma_f32_16x16x32_bf16(a, b11, s1, 0,0,0);
      accI = __builtin_amdgcn_mfma_f32_16x16x32_bf16(a, ivS, accI, 0,0,0);
      a = packa(x2);
      s0 = __builtin_amdgcn_mfma_f32_16x16x32_bf16(a, b20, s0, 0,0,0);
      s1 = __builtin_amdgcn_mfma_f32_16x16x32_bf16(a, b21, s1, 0,0,0);
      accI = __builtin_amdgcn_mfma_f32_16x16x32_bf16(a, ivS, accI, 0,0,0);
      a = packa(x3);
      s0 = __builtin_amdgcn_mfma_f32_16x16x32_bf16(a, b30, s0, 0,0,0);
      s1 = __builtin_amdgcn_mfma_f32_16x16x32_bf16(a, b31, s1, 0,0,0);
      accI = __builtin_amdgcn_mfma_f32_16x16x32_bf16(a, ivS, accI, 0,0,0);
    }
  };

  int kt = ktA;
  while (kt < ktB) {
    if (kt == 0 || kt == 69 || kt == 320) { slow_tile(kt); ++kt; continue; }
    const bool isD = (kt < 69);
    const int segEnd = isD ? 69 : 320;
    const int runEnd = (ktB < segEnd) ? ktB : segEnd;
    const int n4 = (runEnd - kt) & ~3;
    if (n4 > 0) {
      if (isD) run4(kt, kt + n4, accD0, accD1, ivD);
      else     run4(kt, kt + n4, accA0, accA1, ivA);
      kt += n4;
    }
    while (kt < runEnd) { slow_tile(kt); ++kt; }
  }

  float* slab = part + (size_t)ks * PART_STRIDE;
  const int rbase = rb * 64 + w * 16 + hi * 4;
#pragma unroll
  for (int j = 0; j < 4; ++j) {
    size_t ro = (size_t)(rbase + j) * NCOLS;
    slab[ro +  0 + lo] = accG0[j];
    slab[ro + 16 + lo] = accG1[j];
    slab[ro + 32 + lo] = accD0[j];
    slab[ro + 48 + lo] = accD1[j];
    slab[ro + 64 + lo] = accA0[j];
    slab[ro + 80 + lo] = accA1[j];
    if (lo < 3) slab[ro + 96 + lo] = accI[j];
  }
}

// ===========================================================================
// Reduce + epilogue (proven): one row per 128-thread block.
// ===========================================================================
__global__ __launch_bounds__(128) void reduce_k(const int* __restrict__ x,
                                                const float* __restrict__ rate,
                                                const float* __restrict__ part,
                                                int ksplit,
                                                float* __restrict__ out) {
  __shared__ float cnt[3];
  const int r = blockIdx.x;
  const int c = threadIdx.x;

  if (c < 3) {
    float s = 0.f;
    for (int ks = 0; ks < ksplit; ++ks)
      s += part[(size_t)ks * PART_STRIDE + (size_t)r * NCOLS + 96 + c];
    cnt[c] = s;
  }
  __syncthreads();

  float res;
  if (c < EMB) {
    int idx = x[(size_t)r * XC];
    float v = rate[idx * EMB + c];
    float s2 = v * v;
    s2 += __shfl_xor(s2, 1, 32);
    s2 += __shfl_xor(s2, 2, 32);
    s2 += __shfl_xor(s2, 4, 32);
    s2 += __shfl_xor(s2, 8, 32);
    s2 += __shfl_xor(s2, 16, 32);
    float norm = sqrtf(s2);
    float scale = (norm > 1.0f) ? (1.0f / (norm + 1e-7f)) : 1.0f;
    res = v * scale;
  } else {
    int cc = c - EMB;                  // 0..95
    float val = 0.f;
    for (int ks = 0; ks < ksplit; ++ks)
      val += part[(size_t)ks * PART_STRIDE + (size_t)r * NCOLS + cc];
    res = val / cnt[cc >> 5];
  }
  out[(size_t)r * OUTC + c] = res;
}

// ---------------------------------------------------------------------------
extern "C" void kernel_launch(void* const* d_in, const int* in_sizes, int n_in,
                              void* d_out, int out_size, void* d_ws, size_t ws_size,
                              hipStream_t stream) {
  (void)in_sizes; (void)n_in; (void)out_size;
  const int*   x    = (const int*)d_in[0];
  const float* rate = (const float*)d_in[1];
  const float* wg   = (const float*)d_in[2];
  const float* wd   = (const float*)d_in[3];
  const float* wa   = (const float*)d_in[4];
  float* out  = (float*)d_out;
  float* part = (float*)d_ws;

  const size_t slab_bytes = PART_STRIDE * sizeof(float);   // 7.34 MB
  int KS;
  if      (ws_size >= 8 * slab_bytes + WFRAG_BYTES) KS = 8;
  else if (ws_size >= 4 * slab_bytes + WFRAG_BYTES) KS = 4;
  else if (ws_size >= 2 * slab_bytes + WFRAG_BYTES) KS = 2;
  else                                              KS = 1;
  uint4* Wfrag = (uint4*)((char*)d_ws + (size_t)KS * slab_bytes);

  prep_wfrag<<<KT_TOTAL, 256, 0, stream>>>(wg, wd, wa, Wfrag);
  switch (KS) {
    case 8: main_mm<8><<<8 * 256, 256, 0, stream>>>(x, Wfrag, part); break;
    case 4: main_mm<4><<<4 * 256, 256, 0, stream>>>(x, Wfrag, part); break;
    case 2: main_mm<2><<<2 * 256, 256, 0, stream>>>(x, Wfrag, part); break;
    default: main_mm<1><<<1 * 256, 256, 0, stream>>>(x, Wfrag, part); break;
  }
  reduce_k<<<B_ROWS, 128, 0, stream>>>(x, rate, part, KS, out);
}

// Round 12
// 910.969 us; speedup vs baseline: 1.0492x; 1.0492x over previous
//
#include <hip/hip_runtime.h>
#include <hip/hip_bf16.h>

// Problem constants
#define B_ROWS 16384
#define XC     10242      // 1 rate + 25 genre + 2186 director + 8030 actor
#define NGENRE 25
#define NDIR   2186
#define NACT   8030
#define EMB    32
#define KT_TOTAL 321      // ceil(10242/32) k-tiles of 32
#define OUTC   128
#define NCOLS  112        // slab cols: 96 emb + 3 counts + pad
#define PART_STRIDE ((size_t)B_ROWS * NCOLS)
#define WFRAG_BYTES ((size_t)KT_TOTAL * 4 * 64 * 16)   // 1.31 MB

typedef short bf16x8 __attribute__((ext_vector_type(8)));
typedef float f32x4  __attribute__((ext_vector_type(4)));
typedef float f32x4a __attribute__((ext_vector_type(4), aligned(4)));
typedef int   i32x4a __attribute__((ext_vector_type(4), aligned(4)));

// ===========================================================================
// Prep (proven): pre-convert block-diagonal W into bf16 B-fragments,
// fragment-linear. B-frag: lane l holds B[k=kt*32+(l>>4)*8+j][n=l&15].
// 4 slots/kt; boundary tiles (0: genre|director, 69: director|actor) use all
// 4 pre-masked; interior tiles use slots 0,1.
// ===========================================================================
__global__ void prep_wfrag(const float* __restrict__ wg,
                           const float* __restrict__ wd,
                           const float* __restrict__ wa,
                           uint4* __restrict__ Wfrag) {
  const int kt = blockIdx.x;
  const int s  = threadIdx.x >> 6;       // slot 0..3
  const int l  = threadIdx.x & 63;
  const int n  = l & 15;
  const int k0 = kt * 32 + ((l >> 4) << 3);

  unsigned short v[8];
#pragma unroll
  for (int j = 0; j < 8; ++j) {
    const int k = k0 + j;
    float f = 0.f;
    if (kt == 0) {
      if (s < 2) { if (k >= 1 && k < 26) f = wg[(s * 16 + n) * NGENRE + (k - 1)]; }
      else       { if (k >= 26)          f = wd[((s - 2) * 16 + n) * NDIR + (k - 26)]; }
    } else if (kt < 69) {
      if (s < 2) f = wd[(s * 16 + n) * NDIR + (k - 26)];
    } else if (kt == 69) {
      if (s < 2) { if (k < 2212)  f = wd[(s * 16 + n) * NDIR + (k - 26)]; }
      else       { if (k >= 2212) f = wa[((s - 2) * 16 + n) * NACT + (k - 2212)]; }
    } else if (kt < 320) {
      if (s < 2) f = wa[(s * 16 + n) * NACT + (k - 2212)];
    } else {
      if (s < 2 && k < XC) f = wa[(s * 16 + n) * NACT + (k - 2212)];
    }
    __hip_bfloat16 h = __float2bfloat16(f);
    v[j] = *reinterpret_cast<unsigned short*>(&h);
  }
  union { unsigned short u[8]; uint4 q; } cv;
#pragma unroll
  for (int j = 0; j < 8; ++j) cv.u[j] = v[j];
  Wfrag[((size_t)kt * 4 + s) * 64 + l] = cv.q;
}

// ===========================================================================
// Main (exact R10 structure — empirical best): barrier-free, LDS-free,
// group-of-4 k-tiles with all x-loads issued up front (512-B burst per row
// stream), lazy B-frag loads inside do_mfma, no launch-bounds VGPR cap.
// A-frag: lane holds A[m=lane&15][k=(lane>>4)*8+j]; C/D row=(lane>>4)*4+j,
// col=lane&15. Pack: (x0 + (x1<<16)) * 0x3F80 (exact for x in {0,1}).
// ===========================================================================
template<int KS>
__global__ __launch_bounds__(256) void main_mm(const int* __restrict__ x,
                                               const uint4* __restrict__ Wfrag,
                                               float* __restrict__ part) {
  constexpr int PER = (((KT_TOTAL + KS - 1) / KS) + 3) & ~3;   // multiple of 4
  const int t    = threadIdx.x;
  const int rb   = blockIdx.x & 255;
  const int ks   = blockIdx.x >> 8;
  const int ktA  = ks * PER;
  const int ktB  = (ktA + PER < KT_TOTAL) ? ktA + PER : KT_TOTAL;
  const int lane = t & 63;
  const int w    = t >> 6;
  const int lo   = lane & 15, hi = lane >> 4;
  const int* xrow = x + (size_t)(rb * 64 + w * 16 + lo) * XC;

  f32x4 accG0 = {0,0,0,0}, accG1 = {0,0,0,0};
  f32x4 accD0 = {0,0,0,0}, accD1 = {0,0,0,0};
  f32x4 accA0 = {0,0,0,0}, accA1 = {0,0,0,0};
  f32x4 accI  = {0,0,0,0};

  auto load_x8 = [&](int kt, int* dst) {
    int k0 = kt * 32 + hi * 8;
    if (kt < 320) {          // wave-uniform in-bounds: k0+7 <= 10239 < XC
      i32x4a a = *reinterpret_cast<const i32x4a*>(xrow + k0);
      i32x4a b = *reinterpret_cast<const i32x4a*>(xrow + k0 + 4);
      dst[0]=a[0]; dst[1]=a[1]; dst[2]=a[2]; dst[3]=a[3];
      dst[4]=b[0]; dst[5]=b[1]; dst[6]=b[2]; dst[7]=b[3];
    } else {                 // tail tile: per-lane masked scalar loads
#pragma unroll
      for (int j = 0; j < 8; ++j) dst[j] = (k0 + j < XC) ? xrow[k0 + j] : 0;
    }
  };
  auto packa = [&](const int* cx) -> bf16x8 {
    union { unsigned int w4[4]; bf16x8 v; } af;
#pragma unroll
    for (int i = 0; i < 4; ++i)
      af.w4[i] = ((unsigned)cx[2*i] + ((unsigned)cx[2*i+1] << 16)) * 0x3F80u;
    return af.v;
  };
  auto bload = [&](int kt, int s) -> bf16x8 {
    union { uint4 q; bf16x8 v; } c;
    c.q = Wfrag[((size_t)kt * 4 + s) * 64 + lane];
    return c.v;
  };
  auto mkconst = [&](bool on) -> bf16x8 {
    union { unsigned int w4[4]; bf16x8 v; } c;
    unsigned int u = on ? 0x3F803F80u : 0u;
    c.w4[0]=u; c.w4[1]=u; c.w4[2]=u; c.w4[3]=u;
    return c.v;
  };
  const bf16x8 ivD = mkconst(lo == 1);
  const bf16x8 ivA = mkconst(lo == 2);

  auto do_mfma = [&](int kt, bf16x8 a) {
    const int kb = kt * 32 + hi * 8;
    if (kt == 0) {
      accG0 = __builtin_amdgcn_mfma_f32_16x16x32_bf16(a, bload(0,0), accG0, 0,0,0);
      accG1 = __builtin_amdgcn_mfma_f32_16x16x32_bf16(a, bload(0,1), accG1, 0,0,0);
      accD0 = __builtin_amdgcn_mfma_f32_16x16x32_bf16(a, bload(0,2), accD0, 0,0,0);
      accD1 = __builtin_amdgcn_mfma_f32_16x16x32_bf16(a, bload(0,3), accD1, 0,0,0);
      union { unsigned short u[8]; bf16x8 v; } iv;
#pragma unroll
      for (int j = 0; j < 8; ++j) {
        int k = kb + j;
        bool on = (lo == 0) ? (k >= 1 && k < 26) : (lo == 1) ? (k >= 26) : false;
        iv.u[j] = on ? (unsigned short)0x3F80 : (unsigned short)0;
      }
      accI = __builtin_amdgcn_mfma_f32_16x16x32_bf16(a, iv.v, accI, 0,0,0);
    } else if (kt < 69) {
      accD0 = __builtin_amdgcn_mfma_f32_16x16x32_bf16(a, bload(kt,0), accD0, 0,0,0);
      accD1 = __builtin_amdgcn_mfma_f32_16x16x32_bf16(a, bload(kt,1), accD1, 0,0,0);
      accI  = __builtin_amdgcn_mfma_f32_16x16x32_bf16(a, ivD, accI, 0,0,0);
    } else if (kt == 69) {
      accD0 = __builtin_amdgcn_mfma_f32_16x16x32_bf16(a, bload(69,0), accD0, 0,0,0);
      accD1 = __builtin_amdgcn_mfma_f32_16x16x32_bf16(a, bload(69,1), accD1, 0,0,0);
      accA0 = __builtin_amdgcn_mfma_f32_16x16x32_bf16(a, bload(69,2), accA0, 0,0,0);
      accA1 = __builtin_amdgcn_mfma_f32_16x16x32_bf16(a, bload(69,3), accA1, 0,0,0);
      union { unsigned short u[8]; bf16x8 v; } iv;
#pragma unroll
      for (int j = 0; j < 8; ++j) {
        int k = kb + j;
        bool on = (lo == 1) ? (k < 2212) : (lo == 2) ? (k >= 2212) : false;
        iv.u[j] = on ? (unsigned short)0x3F80 : (unsigned short)0;
      }
      accI = __builtin_amdgcn_mfma_f32_16x16x32_bf16(a, iv.v, accI, 0,0,0);
    } else if (kt < 320) {
      accA0 = __builtin_amdgcn_mfma_f32_16x16x32_bf16(a, bload(kt,0), accA0, 0,0,0);
      accA1 = __builtin_amdgcn_mfma_f32_16x16x32_bf16(a, bload(kt,1), accA1, 0,0,0);
      accI  = __builtin_amdgcn_mfma_f32_16x16x32_bf16(a, ivA, accI, 0,0,0);
    } else {
      accA0 = __builtin_amdgcn_mfma_f32_16x16x32_bf16(a, bload(320,0), accA0, 0,0,0);
      accA1 = __builtin_amdgcn_mfma_f32_16x16x32_bf16(a, bload(320,1), accA1, 0,0,0);
      union { unsigned short u[8]; bf16x8 v; } iv;
#pragma unroll
      for (int j = 0; j < 8; ++j) {
        int k = kb + j;
        iv.u[j] = (lo == 2 && k < XC) ? (unsigned short)0x3F80 : (unsigned short)0;
      }
      accI = __builtin_amdgcn_mfma_f32_16x16x32_bf16(a, iv.v, accI, 0,0,0);
    }
  };

  // Group-of-4 k-loop (R10): issue the whole group's x-loads (512-B burst
  // per row stream), then consume tile-by-tile. Statically indexed buffers.
  int xg0[8], xg1[8], xg2[8], xg3[8];
  for (int g = ktA; g < ktB; g += 4) {
    load_x8(g, xg0);
    if (g + 1 < ktB) load_x8(g + 1, xg1);
    if (g + 2 < ktB) load_x8(g + 2, xg2);
    if (g + 3 < ktB) load_x8(g + 3, xg3);

    do_mfma(g, packa(xg0));
    if (g + 1 < ktB) do_mfma(g + 1, packa(xg1));
    if (g + 2 < ktB) do_mfma(g + 2, packa(xg2));
    if (g + 3 < ktB) do_mfma(g + 3, packa(xg3));
  }

  float* slab = part + (size_t)ks * PART_STRIDE;
  const int rbase = rb * 64 + w * 16 + hi * 4;
#pragma unroll
  for (int j = 0; j < 4; ++j) {
    size_t ro = (size_t)(rbase + j) * NCOLS;
    slab[ro +  0 + lo] = accG0[j];
    slab[ro + 16 + lo] = accG1[j];
    slab[ro + 32 + lo] = accD0[j];
    slab[ro + 48 + lo] = accD1[j];
    slab[ro + 64 + lo] = accA0[j];
    slab[ro + 80 + lo] = accA1[j];
    if (lo < 3) slab[ro + 96 + lo] = accI[j];
  }
}

// ===========================================================================
// Reduce + epilogue v2: one row per 128-thread block, but slab reads are
// float4 (28 x 16B coalesced per slab) accumulated in registers, spread to
// the 96 division lanes via LDS. Rate max-norm path unchanged.
// ===========================================================================
__global__ __launch_bounds__(128) void reduce_k(const int* __restrict__ x,
                                                const float* __restrict__ rate,
                                                const float* __restrict__ part,
                                                int ksplit,
                                                float* __restrict__ out) {
  __shared__ float srow[112];
  const int r = blockIdx.x;
  const int c = threadIdx.x;

  if (c < 28) {                       // 28 float4 = 112 floats (96+3+pad)
    f32x4 acc = {0.f, 0.f, 0.f, 0.f};
    for (int ks = 0; ks < ksplit; ++ks) {
      const float* p = part + (size_t)ks * PART_STRIDE + (size_t)r * NCOLS + c * 4;
      f32x4a v = *reinterpret_cast<const f32x4a*>(p);
      acc[0] += v[0]; acc[1] += v[1]; acc[2] += v[2]; acc[3] += v[3];
    }
    srow[c * 4 + 0] = acc[0];
    srow[c * 4 + 1] = acc[1];
    srow[c * 4 + 2] = acc[2];
    srow[c * 4 + 3] = acc[3];
  }
  __syncthreads();

  float res;
  if (c < EMB) {
    int idx = x[(size_t)r * XC];
    float v = rate[idx * EMB + c];
    float s2 = v * v;
    s2 += __shfl_xor(s2, 1, 32);
    s2 += __shfl_xor(s2, 2, 32);
    s2 += __shfl_xor(s2, 4, 32);
    s2 += __shfl_xor(s2, 8, 32);
    s2 += __shfl_xor(s2, 16, 32);
    float norm = sqrtf(s2);
    float scale = (norm > 1.0f) ? (1.0f / (norm + 1e-7f)) : 1.0f;
    res = v * scale;
  } else {
    int cc = c - EMB;                  // 0..95
    res = srow[cc] / srow[96 + (cc >> 5)];
  }
  out[(size_t)r * OUTC + c] = res;
}

// ---------------------------------------------------------------------------
extern "C" void kernel_launch(void* const* d_in, const int* in_sizes, int n_in,
                              void* d_out, int out_size, void* d_ws, size_t ws_size,
                              hipStream_t stream) {
  (void)in_sizes; (void)n_in; (void)out_size;
  const int*   x    = (const int*)d_in[0];
  const float* rate = (const float*)d_in[1];
  const float* wg   = (const float*)d_in[2];
  const float* wd   = (const float*)d_in[3];
  const float* wa   = (const float*)d_in[4];
  float* out  = (float*)d_out;
  float* part = (float*)d_ws;

  const size_t slab_bytes = PART_STRIDE * sizeof(float);   // 7.34 MB
  // KS=4: same resident TLP as KS=8 (blocks/CU is VGPR-capped), half the
  // slab traffic, single dispatch round. Smaller ws falls back.
  int KS;
  if      (ws_size >= 4 * slab_bytes + WFRAG_BYTES) KS = 4;
  else if (ws_size >= 2 * slab_bytes + WFRAG_BYTES) KS = 2;
  else                                              KS = 1;
  uint4* Wfrag = (uint4*)((char*)d_ws + (size_t)KS * slab_bytes);

  prep_wfrag<<<KT_TOTAL, 256, 0, stream>>>(wg, wd, wa, Wfrag);
  switch (KS) {
    case 4: main_mm<4><<<4 * 256, 256, 0, stream>>>(x, Wfrag, part); break;
    case 2: main_mm<2><<<2 * 256, 256, 0, stream>>>(x, Wfrag, part); break;
    default: main_mm<1><<<1 * 256, 256, 0, stream>>>(x, Wfrag, part); break;
  }
  reduce_k<<<B_ROWS, 128, 0, stream>>>(x, rate, part, KS, out);
}